// Round 7
// baseline (777.173 us; speedup 1.0000x reference)
//
#include <hip/hip_runtime.h>
#include <hip/hip_bf16.h>

// Problem constants (B=8, S=256, D=64, G=32, E=256, L=4, NH=8, DH=8)
constexpr int kB  = 8;
constexpr int kS  = 256;
constexpr int kD  = 64;
constexpr int kG  = 32;
constexpr int kE  = 256;
constexpr int kNH = 8;
constexpr int kHD = 256;              // DH*G = 8*32
constexpr int kDG = kD * kG;          // 2048
constexpr int kT  = kB * kS;          // 2048 tokens
constexpr int kNC = 1000;

using bf16x8 = __attribute__((ext_vector_type(8))) short;
using f32x4  = __attribute__((ext_vector_type(4))) float;

__device__ __forceinline__ short f2bf(float f) {
    unsigned u = __float_as_uint(f);
    unsigned r = (u + 0x7FFFu + ((u >> 16) & 1u)) >> 16;   // RNE
    return (short)r;
}

__device__ __forceinline__ float tanh_fast(float x) {
    float a = fabsf(x);
    float e = __expf(-2.f * a);
    float t = (1.f - e) / (1.f + e);
    return copysignf(t, x);
}

// ---------------- first LN fused with residual-stream copy ----------------
// X = x_in (copy), A = layer_norm2d(x_in)
__global__ __launch_bounds__(256) void lncopy_kernel(const float* __restrict__ Xin,
                                                     const float* __restrict__ w,
                                                     const float* __restrict__ b,
                                                     float* __restrict__ X,
                                                     float* __restrict__ A) {
    int t = blockIdx.x, tid = threadIdx.x;
    const float* xp = Xin + (size_t)t * kDG;
    __shared__ float r1[256], r2[256];
    float v[8], s = 0.f, ss = 0.f;
#pragma unroll
    for (int j = 0; j < 8; j++) {
        float x = xp[tid + j * 256];
        v[j] = x; s += x; ss += x * x;
    }
    r1[tid] = s; r2[tid] = ss; __syncthreads();
    for (int o = 128; o > 0; o >>= 1) {
        if (tid < o) { r1[tid] += r1[tid + o]; r2[tid] += r2[tid + o]; }
        __syncthreads();
    }
    float mean = r1[0] * (1.f / kDG);
    float var  = r2[0] * (1.f / kDG) - mean * mean;
    float rstd = rsqrtf(var + 1e-5f);
    float* xo = X + (size_t)t * kDG;
    float* ao = A + (size_t)t * kDG;
#pragma unroll
    for (int j = 0; j < 8; j++) {
        int jj = tid + j * 256;
        xo[jj] = v[j];
        ao[jj] = (v[j] - mean) * rstd * w[jj] + b[jj];
    }
}

// ---------------- residual + manifold_norm + next layer_norm (fused) -------
// X = mn(X + gamma*H)  (written back);  A = LN2d(X) * w + b
__global__ __launch_bounds__(256) void resmn_ln_kernel(float* __restrict__ X,
                                                       const float* __restrict__ H,
                                                       const float* __restrict__ gamma,
                                                       const float* __restrict__ w,
                                                       const float* __restrict__ b,
                                                       float* __restrict__ A) {
    int t = blockIdx.x, tid = threadIdx.x;
    int g8 = tid >> 5, lane = tid & 31;
    __shared__ float r1[256], r2[256];
    float xn[8];
    float s = 0.f, ss = 0.f;
#pragma unroll
    for (int j = 0; j < 8; j++) {
        int d = j * 8 + g8;
        size_t idx = (size_t)t * kDG + d * kG + lane;
        float v = X[idx] + gamma[d * kG + lane] * H[idx];
        float sq = v * v;
#pragma unroll
        for (int m = 16; m > 0; m >>= 1) sq += __shfl_xor(sq, m, 32);
        float xv = v / (sqrtf(sq) + 1e-6f);
        X[idx] = xv;
        xn[j] = xv;
        s += xv; ss += xv * xv;
    }
    r1[tid] = s; r2[tid] = ss; __syncthreads();
    for (int o = 128; o > 0; o >>= 1) {
        if (tid < o) { r1[tid] += r1[tid + o]; r2[tid] += r2[tid + o]; }
        __syncthreads();
    }
    float mean = r1[0] * (1.f / kDG);
    float var  = r2[0] * (1.f / kDG) - mean * mean;
    float rstd = rsqrtf(var + 1e-5f);
#pragma unroll
    for (int j = 0; j < 8; j++) {
        int d = j * 8 + g8;
        size_t idx = (size_t)t * kDG + d * kG + lane;
        A[idx] = (xn[j] - mean) * rstd * w[d * kG + lane] + b[d * kG + lane];
    }
}

// ---------------- plain residual + manifold_norm (last layer) ----------------
__global__ __launch_bounds__(256) void resmn_kernel(float* __restrict__ X,
                                                    const float* __restrict__ H,
                                                    const float* __restrict__ gamma) {
    int gid = blockIdx.x * 8 + (threadIdx.x >> 5);
    int lane = threadIdx.x & 31;
    int d = gid % kD;
    size_t idx = (size_t)gid * kG + lane;
    float v = X[idx] + gamma[d * kG + lane] * H[idx];
    float sq = v * v;
#pragma unroll
    for (int m = 16; m > 0; m >>= 1) sq += __shfl_xor(sq, m, 32);
    X[idx] = v / (sqrtf(sq) + 1e-6f);
}

// ---------------- scalar fp32 versor_linear (kept ONLY for final Wr: scan-tree
// error analysis — 256 leaves combine — forbids bf16 here) ----------------
__global__ __launch_bounds__(256) void vlin_kernel(const float* __restrict__ X,
                                                   const float* __restrict__ W,
                                                   const float* __restrict__ bias,
                                                   float* __restrict__ Out) {
    __shared__ float sx[kDG];      // 8 KB
    __shared__ float sw[kD * kD];  // 16 KB
    int t = blockIdx.x, tid = threadIdx.x;
    const float* xp = X + (size_t)t * kDG;
    for (int j = tid; j < kDG; j += 256) sx[j] = xp[j];
    for (int j = tid; j < kD * kD; j += 256) sw[j] = W[j];
    __syncthreads();
    int g = tid & 31, ob = tid >> 5;
    float* op = Out + (size_t)t * kDG;
    for (int o = ob; o < kD; o += 8) {
        float acc = bias[o * kG + g];
        const float* wr = sw + o * kD;
#pragma unroll
        for (int i = 0; i < kD; i++) acc += wr[i] * sx[i * kG + g];
        op[o * kG + g] = acc;
    }
}

// ---------------- MFMA GEMM over (t,g) columns (Wo path / MLP1) -------------
template<int MT, bool MLP1OUT>
__global__ __launch_bounds__(256, 2) void gemm_tg_kernel(
    const float* __restrict__ X, const float* __restrict__ W,
    const float* __restrict__ bias, float* __restrict__ outF,
    unsigned short* __restrict__ outH) {
    constexpr int M = MT * 16;
    constexpr int WS = 64 + 8;                 // bf16 row stride
    __shared__ short sW[M * WS];
    __shared__ short sXT[4][32][WS];           // per-wave token, [g][i]

    const int tid = threadIdx.x, wave = tid >> 6, lane = tid & 63;
    const int l16 = lane & 15, quad = lane >> 4;
    const int tok = blockIdx.x * 4 + wave;

    for (int j = tid * 4; j < M * 64; j += 1024) {
        const float4 w4 = *(const float4*)(W + j);
        int o = j >> 6, i = j & 63;
        *(short4*)&sW[o * WS + i] = make_short4(f2bf(w4.x), f2bf(w4.y), f2bf(w4.z), f2bf(w4.w));
    }
    {
        const int g4 = (lane & 7) * 4;
        const int i0 = (lane >> 3) * 8;
        const float* xp = X + (size_t)tok * kDG;
#pragma unroll
        for (int half = 0; half < 2; ++half) {
            float4 vr[4];
#pragma unroll
            for (int r = 0; r < 4; ++r)
                vr[r] = *(const float4*)(xp + (i0 + half * 4 + r) * kG + g4);
#pragma unroll
            for (int gg = 0; gg < 4; ++gg)
                *(short4*)&sXT[wave][g4 + gg][i0 + half * 4] =
                    make_short4(f2bf((&vr[0].x)[gg]), f2bf((&vr[1].x)[gg]),
                                f2bf((&vr[2].x)[gg]), f2bf((&vr[3].x)[gg]));
        }
    }
    __syncthreads();

    bf16x8 bfr[2][2];
#pragma unroll
    for (int c = 0; c < 2; ++c)
#pragma unroll
        for (int nt = 0; nt < 2; ++nt)
            bfr[c][nt] = *(const bf16x8*)&sXT[wave][nt * 16 + l16][c * 32 + quad * 8];

    f32x4 acc[MT][2];
#pragma unroll
    for (int mt = 0; mt < MT; ++mt)
#pragma unroll
        for (int nt = 0; nt < 2; ++nt) acc[mt][nt] = (f32x4){0.f, 0.f, 0.f, 0.f};

#pragma unroll
    for (int mt = 0; mt < MT; ++mt)
#pragma unroll
        for (int c = 0; c < 2; ++c) {
            bf16x8 afr = *(const bf16x8*)&sW[(mt * 16 + l16) * WS + c * 32 + quad * 8];
#pragma unroll
            for (int nt = 0; nt < 2; ++nt)
                acc[mt][nt] = __builtin_amdgcn_mfma_f32_16x16x32_bf16(afr, bfr[c][nt], acc[mt][nt], 0, 0, 0);
        }

    if (!MLP1OUT) {
        float* op = outF + (size_t)tok * M * kG;
#pragma unroll
        for (int mt = 0; mt < MT; ++mt)
#pragma unroll
            for (int nt = 0; nt < 2; ++nt) {
                int g = nt * 16 + l16;
#pragma unroll
                for (int r = 0; r < 4; ++r) {
                    int o = mt * 16 + quad * 4 + r;
                    op[o * kG + g] = acc[mt][nt][r] + bias[o * kG + g];
                }
            }
    } else {
        unsigned short* op = outH + (size_t)tok * M * kG;   // [t][g][M]
#pragma unroll
        for (int mt = 0; mt < MT; ++mt)
#pragma unroll
            for (int nt = 0; nt < 2; ++nt) {
                int g = nt * 16 + l16;
                int e0 = mt * 16 + quad * 4;
                short4 s4;
                s4.x = f2bf(tanh_fast(acc[mt][nt][0] + bias[(e0 + 0) * kG + g]));
                s4.y = f2bf(tanh_fast(acc[mt][nt][1] + bias[(e0 + 1) * kG + g]));
                s4.z = f2bf(tanh_fast(acc[mt][nt][2] + bias[(e0 + 2) * kG + g]));
                s4.w = f2bf(tanh_fast(acc[mt][nt][3] + bias[(e0 + 3) * kG + g]));
                *(short4*)&op[g * M + e0] = s4;
            }
    }
}

// ---------------- fused Q/K/V GEMM (reads A once) ----------------
__global__ __launch_bounds__(256, 2) void gemm_qkv_kernel(
    const float* __restrict__ X,
    const float* __restrict__ Wq, const float* __restrict__ Wk, const float* __restrict__ Wv,
    const float* __restrict__ bq, const float* __restrict__ bk, const float* __restrict__ bv,
    float* __restrict__ Q, float* __restrict__ K, float* __restrict__ V) {
    constexpr int WS = 64 + 8;
    __shared__ short sW[3 * 64 * WS];          // 27.6 KB
    __shared__ short sXT[4][32][WS];           // 18.4 KB

    const int tid = threadIdx.x, wave = tid >> 6, lane = tid & 63;
    const int l16 = lane & 15, quad = lane >> 4;
    const int tok = blockIdx.x * 4 + wave;

    const float* Wp[3] = {Wq, Wk, Wv};
#pragma unroll
    for (int w = 0; w < 3; ++w)
        for (int j = tid * 4; j < 64 * 64; j += 1024) {
            const float4 w4 = *(const float4*)(Wp[w] + j);
            int o = j >> 6, i = j & 63;
            *(short4*)&sW[w * 64 * WS + o * WS + i] =
                make_short4(f2bf(w4.x), f2bf(w4.y), f2bf(w4.z), f2bf(w4.w));
        }
    {
        const int g4 = (lane & 7) * 4;
        const int i0 = (lane >> 3) * 8;
        const float* xp = X + (size_t)tok * kDG;
#pragma unroll
        for (int half = 0; half < 2; ++half) {
            float4 vr[4];
#pragma unroll
            for (int r = 0; r < 4; ++r)
                vr[r] = *(const float4*)(xp + (i0 + half * 4 + r) * kG + g4);
#pragma unroll
            for (int gg = 0; gg < 4; ++gg)
                *(short4*)&sXT[wave][g4 + gg][i0 + half * 4] =
                    make_short4(f2bf((&vr[0].x)[gg]), f2bf((&vr[1].x)[gg]),
                                f2bf((&vr[2].x)[gg]), f2bf((&vr[3].x)[gg]));
        }
    }
    __syncthreads();

    bf16x8 bfr[2][2];
#pragma unroll
    for (int c = 0; c < 2; ++c)
#pragma unroll
        for (int nt = 0; nt < 2; ++nt)
            bfr[c][nt] = *(const bf16x8*)&sXT[wave][nt * 16 + l16][c * 32 + quad * 8];

    f32x4 acc[3][4][2];
#pragma unroll
    for (int w = 0; w < 3; ++w)
#pragma unroll
        for (int mt = 0; mt < 4; ++mt)
#pragma unroll
            for (int nt = 0; nt < 2; ++nt) acc[w][mt][nt] = (f32x4){0.f, 0.f, 0.f, 0.f};

#pragma unroll
    for (int w = 0; w < 3; ++w)
#pragma unroll
        for (int mt = 0; mt < 4; ++mt)
#pragma unroll
            for (int c = 0; c < 2; ++c) {
                bf16x8 afr = *(const bf16x8*)&sW[w * 64 * WS + (mt * 16 + l16) * WS + c * 32 + quad * 8];
#pragma unroll
                for (int nt = 0; nt < 2; ++nt)
                    acc[w][mt][nt] = __builtin_amdgcn_mfma_f32_16x16x32_bf16(afr, bfr[c][nt], acc[w][mt][nt], 0, 0, 0);
            }

    float* Op[3] = {Q, K, V};
    const float* Bp[3] = {bq, bk, bv};
#pragma unroll
    for (int w = 0; w < 3; ++w) {
        float* op = Op[w] + (size_t)tok * kDG;
#pragma unroll
        for (int mt = 0; mt < 4; ++mt)
#pragma unroll
            for (int nt = 0; nt < 2; ++nt) {
                int g = nt * 16 + l16;
#pragma unroll
                for (int r = 0; r < 4; ++r) {
                    int o = mt * 16 + quad * 4 + r;
                    op[o * kG + g] = acc[w][mt][nt][r] + Bp[w][o * kG + g];
                }
            }
    }
}

// ---------------- MLP second half ----------------
__global__ __launch_bounds__(256, 2) void mlp2_kernel(
    const unsigned short* __restrict__ Mb,  // [t][32][256] bf16
    const float* __restrict__ W2,           // [64][256]
    const float* __restrict__ b2,           // [64][32]
    float* __restrict__ Out) {              // [t][64][32]
    constexpr int WS = 256 + 8;
    __shared__ short sW[64 * WS];
    const int tid = threadIdx.x, wave = tid >> 6, lane = tid & 63;
    const int l16 = lane & 15, quad = lane >> 4;
    const int tok = blockIdx.x * 4 + wave;

    for (int j = tid * 4; j < 64 * 256; j += 1024) {
        const float4 w4 = *(const float4*)(W2 + j);
        int o = j >> 8, i = j & 255;
        *(short4*)&sW[o * WS + i] = make_short4(f2bf(w4.x), f2bf(w4.y), f2bf(w4.z), f2bf(w4.w));
    }
    __syncthreads();

    f32x4 acc[4][2];
#pragma unroll
    for (int mt = 0; mt < 4; ++mt)
#pragma unroll
        for (int nt = 0; nt < 2; ++nt) acc[mt][nt] = (f32x4){0.f, 0.f, 0.f, 0.f};

    const unsigned short* mp = Mb + (size_t)tok * kG * kE;
#pragma unroll
    for (int c = 0; c < 8; ++c) {
        bf16x8 bfr[2];
#pragma unroll
        for (int nt = 0; nt < 2; ++nt)
            bfr[nt] = *(const bf16x8*)&mp[(nt * 16 + l16) * kE + c * 32 + quad * 8];
#pragma unroll
        for (int mt = 0; mt < 4; ++mt) {
            bf16x8 afr = *(const bf16x8*)&sW[(mt * 16 + l16) * WS + c * 32 + quad * 8];
#pragma unroll
            for (int nt = 0; nt < 2; ++nt)
                acc[mt][nt] = __builtin_amdgcn_mfma_f32_16x16x32_bf16(afr, bfr[nt], acc[mt][nt], 0, 0, 0);
        }
    }

    float* op = Out + (size_t)tok * kDG;
#pragma unroll
    for (int mt = 0; mt < 4; ++mt)
#pragma unroll
        for (int nt = 0; nt < 2; ++nt) {
            int g = nt * 16 + l16;
#pragma unroll
            for (int r = 0; r < 4; ++r) {
                int o = mt * 16 + quad * 4 + r;
                op[o * kG + g] = acc[mt][nt][r] + b2[o * kG + g];
            }
        }
}

// ---------------- MFMA flash-style attention ----------------
constexpr int QSTR = 264;
constexpr int VSTR = 40;

__global__ __launch_bounds__(256) void attn_mfma_kernel(const float* __restrict__ Q,
                                                        const float* __restrict__ K,
                                                        const float* __restrict__ V,
                                                        float* __restrict__ O) {
    __shared__ short sQ[64 * QSTR];
    __shared__ short sKV[256 * VSTR];

    const int qt = blockIdx.x, h = blockIdx.y, b = blockIdx.z;
    const int tid = threadIdx.x;
    const int wave = tid >> 6, lane = tid & 63;
    const int l16 = lane & 15, quad = lane >> 4;

    const size_t bh = (size_t)b * kS * kDG + (size_t)h * kHD;

    {
        int r0 = tid >> 6;
        int c4 = lane << 2;
        for (int it = 0; it < 16; ++it) {
            int row = it * 4 + r0;
            const float4 v = *(const float4*)(Q + bh + (size_t)(qt * 64 + row) * kDG + c4);
            short4 p = make_short4(f2bf(v.x), f2bf(v.y), f2bf(v.z), f2bf(v.w));
            *(short4*)&sQ[row * QSTR + c4] = p;
        }
    }
    __syncthreads();

    bf16x8 afrag[8];
    {
        int row = wave * 16 + l16;
#pragma unroll
        for (int c = 0; c < 8; ++c)
            afrag[c] = *(const bf16x8*)&sQ[row * QSTR + c * 32 + quad * 8];
    }

    f32x4 acc[16];
#pragma unroll
    for (int i = 0; i < 16; ++i) acc[i] = (f32x4){0.f, 0.f, 0.f, 0.f};

    for (int kt = 0; kt < 8; ++kt) {
        __syncthreads();
        {
            int r0 = tid >> 6;
            int c4 = lane << 2;
            for (int it = 0; it < 8; ++it) {
                int row = it * 4 + r0;
                const float4 v = *(const float4*)(K + bh + (size_t)(kt * 32 + row) * kDG + c4);
                short4 p = make_short4(f2bf(v.x), f2bf(v.y), f2bf(v.z), f2bf(v.w));
                *(short4*)&sKV[row * QSTR + c4] = p;
            }
        }
        __syncthreads();
#pragma unroll
        for (int nt = 0; nt < 2; ++nt) {
            int key = nt * 16 + l16;
            f32x4 a = acc[kt * 2 + nt];
#pragma unroll
            for (int c = 0; c < 8; ++c) {
                bf16x8 bfrag = *(const bf16x8*)&sKV[key * QSTR + c * 32 + quad * 8];
                a = __builtin_amdgcn_mfma_f32_16x16x32_bf16(afrag[c], bfrag, a, 0, 0, 0);
            }
            acc[kt * 2 + nt] = a;
        }
    }
    __syncthreads();

    float inv[4];
#pragma unroll
    for (int r = 0; r < 4; ++r) {
        float m = -1e30f;
#pragma unroll
        for (int t = 0; t < 16; ++t) m = fmaxf(m, acc[t][r]);
#pragma unroll
        for (int off = 1; off < 16; off <<= 1) m = fmaxf(m, __shfl_xor(m, off, 16));
        float s = 0.f;
#pragma unroll
        for (int t = 0; t < 16; ++t) {
            float p = __expf((acc[t][r] - m) * 0.0625f);
            acc[t][r] = p; s += p;
        }
#pragma unroll
        for (int off = 1; off < 16; off <<= 1) s += __shfl_xor(s, off, 16);
        inv[r] = 1.f / s;
    }

#pragma unroll
    for (int t = 0; t < 16; ++t)
#pragma unroll
        for (int r = 0; r < 4; ++r)
            sQ[(wave * 16 + quad * 4 + r) * QSTR + t * 16 + l16] = f2bf(acc[t][r]);

    f32x4 oacc[16];
#pragma unroll
    for (int i = 0; i < 16; ++i) oacc[i] = (f32x4){0.f, 0.f, 0.f, 0.f};

    for (int vt = 0; vt < 8; ++vt) {
        __syncthreads();
        {
            int kb = tid >> 5;
            for (int it = 0; it < 2; ++it) {
                int db = (tid & 31) + it * 32;
                float4 vr[4];
#pragma unroll
                for (int r = 0; r < 4; ++r)
                    vr[r] = *(const float4*)(V + bh + (size_t)(vt * 32 + kb * 4 + r) * kDG + db * 4);
#pragma unroll
                for (int i = 0; i < 4; ++i) {
                    short4 p = make_short4(f2bf((&vr[0].x)[i]), f2bf((&vr[1].x)[i]),
                                           f2bf((&vr[2].x)[i]), f2bf((&vr[3].x)[i]));
                    *(short4*)&sKV[(db * 4 + i) * VSTR + kb * 4] = p;
                }
            }
        }
        __syncthreads();
        bf16x8 pfrag = *(const bf16x8*)&sQ[(wave * 16 + l16) * QSTR + vt * 32 + quad * 8];
#pragma unroll
        for (int dt = 0; dt < 16; ++dt) {
            bf16x8 vfrag = *(const bf16x8*)&sKV[(dt * 16 + l16) * VSTR + quad * 8];
            oacc[dt] = __builtin_amdgcn_mfma_f32_16x16x32_bf16(pfrag, vfrag, oacc[dt], 0, 0, 0);
        }
    }

    {
        int qrow = qt * 64 + wave * 16 + quad * 4;
#pragma unroll
        for (int dt = 0; dt < 16; ++dt)
#pragma unroll
            for (int r = 0; r < 4; ++r)
                O[bh + (size_t)(qrow + r) * kDG + dt * 16 + l16] = oacc[dt][r] * inv[r];
    }
}

// ---------------- gp node: out = mn(gp(x, y)), x = later operand ------------
// out_k = sum_a sign(a, a^k) * x_a * y_{a^k}; msk bit a = sign<0 for this lane.
__device__ __forceinline__ float gp_mn(float x, float y, unsigned msk) {
    float acc = 0.f;
#pragma unroll
    for (int a = 0; a < 32; ++a) {
        float v = __shfl(x, a, 32) * __shfl_xor(y, a, 32);
        acc += __int_as_float(__float_as_int(v) ^ (int)((msk >> a) << 31));
    }
    float sq = acc * acc;
#pragma unroll
    for (int m = 16; m > 0; m >>= 1) sq += __shfl_xor(sq, m, 32);
    return acc / (sqrtf(sq) + 1e-6f);
}

// ---------------- fused rotinit + re-associated reduction ----------------
// gp is associative and mn() only rescales by a positive scalar, so the final
// pooled DIRECTION is association-independent (scalars commute through the
// bilinear gp; final mn renormalizes).  Re-associate for parallelism:
// 32 groups x (8-leaf sequential fold, 7 nodes) then 5-level tree (31 nodes).
// Critical path 12 node-steps (vs 34), occupancy up to 32 waves/CU.
__global__ __launch_bounds__(1024) void scanfused2_kernel(const float* __restrict__ Dl,
                                                          float* __restrict__ pooled) {
    __shared__ float sLeaf[256 * 32];   // 32 KB
    __shared__ float sPart[32 * 32];    // 4 KB
    const int tid = threadIdx.x;
    const int b = blockIdx.x >> 6, d = blockIdx.x & 63;
    const int grp = tid >> 5, lane = tid & 31;   // 32 groups of 32 lanes

    // per-lane sign bitmask: bit a = 1 iff GP_TABLE sign for (a, a^lane) < 0
    unsigned msk = 0;
#pragma unroll
    for (int a = 0; a < 32; ++a) {
        int bb = a ^ lane;
        int ssum = (a & bb) >> 4;                // SIG[4] = -1 metric term
        for (int tt = a >> 1; tt; tt >>= 1) ssum += __popc(tt & bb);
        msk |= (unsigned)(ssum & 1) << a;
    }

    // load delta + rotinit for this group's 8 leaves: v0 = mn(0.5*delta + e0)
    const float* Dp = Dl + ((size_t)b * kS * kD + d) * kG;
#pragma unroll
    for (int j = 0; j < 8; ++j) {
        int p = grp * 8 + j;
        float v = 0.5f * Dp[(size_t)p * kDG + lane] + (lane == 0 ? 1.f : 0.f);
        float sq = v * v;
#pragma unroll
        for (int m = 16; m > 0; m >>= 1) sq += __shfl_xor(sq, m, 32);
        sLeaf[p * 32 + lane] = v / (sqrtf(sq) + 1e-6f);
    }
    // group reads only leaves it wrote itself (same-wave ordering) — no barrier

    // stage A: ordered fold of leaves [8g .. 8g+7]  (r = later ∘ earlier)
    float r = sLeaf[(grp * 8) * 32 + lane];
#pragma unroll
    for (int j = 1; j < 8; ++j) {
        float x = sLeaf[(grp * 8 + j) * 32 + lane];
        r = gp_mn(x, r, msk);
    }
    sPart[grp * 32 + lane] = r;
    __syncthreads();

    // stage B: 5-level ordered tree over 32 partials
    for (int n = 16; n >= 1; n >>= 1) {
        float rv = 0.f;
        if (grp < n) {
            float x = sPart[(2 * grp + 1) * 32 + lane];   // later
            float y = sPart[(2 * grp) * 32 + lane];       // earlier
            rv = gp_mn(x, y, msk);
        }
        __syncthreads();
        if (grp < n) sPart[grp * 32 + lane] = rv;
        __syncthreads();
    }
    if (tid < 32) pooled[((size_t)b * kD + d) * kG + lane] = sPart[lane];
}

// ---------------- classifier: wave per class, pooled staged in LDS ----------
__global__ __launch_bounds__(256) void cls2_kernel(const float* __restrict__ P,   // [8][2048]
                                                   const float* __restrict__ Wc,
                                                   const float* __restrict__ bc,
                                                   float* __restrict__ out) {
    __shared__ float sp[kB * kDG];   // 64 KB
    const int tid = threadIdx.x, wave = tid >> 6, lane = tid & 63;
    for (int j = tid * 4; j < kB * kDG; j += 1024)
        *(float4*)&sp[j] = *(const float4*)(P + j);
    __syncthreads();

    const int c = blockIdx.x * 4 + wave;
    const float* w = Wc + (size_t)c * kDG;
    float acc[kB];
#pragma unroll
    for (int b = 0; b < kB; ++b) acc[b] = 0.f;
#pragma unroll
    for (int cc = 0; cc < 8; ++cc) {
        const float4 w4 = *(const float4*)(w + cc * 256 + lane * 4);
#pragma unroll
        for (int b = 0; b < kB; ++b) {
            const float4 p4 = *(const float4*)&sp[b * kDG + cc * 256 + lane * 4];
            acc[b] += w4.x * p4.x + w4.y * p4.y + w4.z * p4.z + w4.w * p4.w;
        }
    }
#pragma unroll
    for (int b = 0; b < kB; ++b)
#pragma unroll
        for (int off = 32; off > 0; off >>= 1) acc[b] += __shfl_xor(acc[b], off, 64);
    if (lane == 0) {
        float bias = bc[c];
#pragma unroll
        for (int b = 0; b < kB; ++b) out[b * kNC + c] = acc[b] + bias;
    }
}

extern "C" void kernel_launch(void* const* d_in, const int* in_sizes, int n_in,
                              void* d_out, int out_size, void* d_ws, size_t ws_size,
                              hipStream_t stream) {
    const float* x_in = (const float*)d_in[0];
    const float* Wq   = (const float*)d_in[1];
    const float* bq   = (const float*)d_in[2];
    const float* Wk   = (const float*)d_in[3];
    const float* bk   = (const float*)d_in[4];
    const float* Wv   = (const float*)d_in[5];
    const float* bv   = (const float*)d_in[6];
    const float* Wo   = (const float*)d_in[7];
    const float* bo   = (const float*)d_in[8];
    const float* ln1w = (const float*)d_in[9];
    const float* ln1b = (const float*)d_in[10];
    const float* ln2w = (const float*)d_in[11];
    const float* ln2b = (const float*)d_in[12];
    const float* gm1  = (const float*)d_in[13];
    const float* gm2  = (const float*)d_in[14];
    const float* W1   = (const float*)d_in[15];
    const float* b1   = (const float*)d_in[16];
    const float* W2   = (const float*)d_in[17];
    const float* b2   = (const float*)d_in[18];
    const float* Wr   = (const float*)d_in[19];
    const float* br   = (const float*)d_in[20];
    const float* Wc   = (const float*)d_in[21];
    const float* bc   = (const float*)d_in[22];

    const size_t NEL = (size_t)kT * kDG;
    float* F  = (float*)d_ws;
    float* X  = F;
    float* A  = F + NEL;
    float* Qb = F + 2 * NEL;
    float* Kb = F + 3 * NEL;
    float* Vb = F + 4 * NEL;
    unsigned short* Mb = (unsigned short*)Kb;   // bf16 [t][32][256], reuses Kb+Vb
    float* pooled = Qb;                         // 16K floats, Qb free at scan time

    lncopy_kernel<<<kT, 256, 0, stream>>>(x_in, ln1w, ln1b, X, A);

    for (int l = 0; l < 4; l++) {
        gemm_qkv_kernel<<<kT / 4, 256, 0, stream>>>(A,
            Wq + l * kD * kD, Wk + l * kD * kD, Wv + l * kD * kD,
            bq + l * kDG, bk + l * kDG, bv + l * kDG, Qb, Kb, Vb);
        attn_mfma_kernel<<<dim3(4, kNH, kB), 256, 0, stream>>>(Qb, Kb, Vb, A);
        gemm_tg_kernel<4, false><<<kT / 4, 256, 0, stream>>>(A, Wo + l * kD * kD, bo + l * kDG, Qb, nullptr);
        resmn_ln_kernel<<<kT, 256, 0, stream>>>(X, Qb, gm1 + l * kDG, ln2w + l * kDG, ln2b + l * kDG, A);
        gemm_tg_kernel<16, true><<<kT / 4, 256, 0, stream>>>(A, W1 + l * kE * kD, b1 + l * kE * kG, nullptr, Mb);
        mlp2_kernel<<<kT / 4, 256, 0, stream>>>(Mb, W2 + l * kD * kE, b2 + l * kDG, Qb);
        if (l < 3)
            resmn_ln_kernel<<<kT, 256, 0, stream>>>(X, Qb, gm2 + l * kDG,
                ln1w + (l + 1) * kDG, ln1b + (l + 1) * kDG, A);
        else
            resmn_kernel<<<kT * kD / 8, 256, 0, stream>>>(X, Qb, gm2 + l * kDG);
    }

    // delta (fp32, error-sensitive) -> fused rotinit + re-associated reduction
    vlin_kernel<<<kT, 256, 0, stream>>>(X, Wr, br, A);
    scanfused2_kernel<<<kB * kD, 1024, 0, stream>>>(A, pooled);
    cls2_kernel<<<kNC / 4, 256, 0, stream>>>(pooled, Wc, bc, (float*)d_out);
}

// Round 8
// 657.343 us; speedup vs baseline: 1.1823x; 1.1823x over previous
//
#include <hip/hip_runtime.h>
#include <hip/hip_bf16.h>

// Problem constants (B=8, S=256, D=64, G=32, E=256, L=4, NH=8, DH=8)
constexpr int kB  = 8;
constexpr int kS  = 256;
constexpr int kD  = 64;
constexpr int kG  = 32;
constexpr int kE  = 256;
constexpr int kNH = 8;
constexpr int kHD = 256;              // DH*G = 8*32
constexpr int kDG = kD * kG;          // 2048
constexpr int kT  = kB * kS;          // 2048 tokens
constexpr int kNC = 1000;

using bf16x8 = __attribute__((ext_vector_type(8))) short;
using f32x4  = __attribute__((ext_vector_type(4))) float;

__device__ __forceinline__ short f2bf(float f) {
    unsigned u = __float_as_uint(f);
    unsigned r = (u + 0x7FFFu + ((u >> 16) & 1u)) >> 16;   // RNE
    return (short)r;
}

__device__ __forceinline__ float tanh_fast(float x) {
    float a = fabsf(x);
    float e = __expf(-2.f * a);
    float t = (1.f - e) / (1.f + e);
    return copysignf(t, x);
}

// ---------------- LN of x_in (layer 0), A only — X copy eliminated ----------
__global__ __launch_bounds__(256) void ln_kernel(const float* __restrict__ Xin,
                                                 const float* __restrict__ w,
                                                 const float* __restrict__ b,
                                                 float* __restrict__ A) {
    int t = blockIdx.x, tid = threadIdx.x;
    const float* xp = Xin + (size_t)t * kDG;
    __shared__ float r1[256], r2[256];
    float v[8], s = 0.f, ss = 0.f;
#pragma unroll
    for (int j = 0; j < 8; j++) {
        float x = xp[tid + j * 256];
        v[j] = x; s += x; ss += x * x;
    }
    r1[tid] = s; r2[tid] = ss; __syncthreads();
    for (int o = 128; o > 0; o >>= 1) {
        if (tid < o) { r1[tid] += r1[tid + o]; r2[tid] += r2[tid + o]; }
        __syncthreads();
    }
    float mean = r1[0] * (1.f / kDG);
    float var  = r2[0] * (1.f / kDG) - mean * mean;
    float rstd = rsqrtf(var + 1e-5f);
    float* ao = A + (size_t)t * kDG;
#pragma unroll
    for (int j = 0; j < 8; j++) {
        int jj = tid + j * 256;
        ao[jj] = (v[j] - mean) * rstd * w[jj] + b[jj];
    }
}

// ---------------- residual + manifold_norm + next layer_norm (fused) -------
// Xout = mn(Xin + gamma*H);  A = LN2d(Xout) * w + b.  (Xin may be x_in.)
__global__ __launch_bounds__(256) void resmn_ln_kernel(const float* __restrict__ Xin,
                                                       float* __restrict__ Xout,
                                                       const float* __restrict__ H,
                                                       const float* __restrict__ gamma,
                                                       const float* __restrict__ w,
                                                       const float* __restrict__ b,
                                                       float* __restrict__ A) {
    int t = blockIdx.x, tid = threadIdx.x;
    int g8 = tid >> 5, lane = tid & 31;
    __shared__ float r1[256], r2[256];
    float xn[8];
    float s = 0.f, ss = 0.f;
#pragma unroll
    for (int j = 0; j < 8; j++) {
        int d = j * 8 + g8;
        size_t idx = (size_t)t * kDG + d * kG + lane;
        float v = Xin[idx] + gamma[d * kG + lane] * H[idx];
        float sq = v * v;
#pragma unroll
        for (int m = 16; m > 0; m >>= 1) sq += __shfl_xor(sq, m, 32);
        float xv = v / (sqrtf(sq) + 1e-6f);
        Xout[idx] = xv;
        xn[j] = xv;
        s += xv; ss += xv * xv;
    }
    r1[tid] = s; r2[tid] = ss; __syncthreads();
    for (int o = 128; o > 0; o >>= 1) {
        if (tid < o) { r1[tid] += r1[tid + o]; r2[tid] += r2[tid + o]; }
        __syncthreads();
    }
    float mean = r1[0] * (1.f / kDG);
    float var  = r2[0] * (1.f / kDG) - mean * mean;
    float rstd = rsqrtf(var + 1e-5f);
#pragma unroll
    for (int j = 0; j < 8; j++) {
        int d = j * 8 + g8;
        size_t idx = (size_t)t * kDG + d * kG + lane;
        A[idx] = (xn[j] - mean) * rstd * w[d * kG + lane] + b[d * kG + lane];
    }
}

// ---------------- plain residual + manifold_norm (last layer) ----------------
__global__ __launch_bounds__(256) void resmn_kernel(float* __restrict__ X,
                                                    const float* __restrict__ H,
                                                    const float* __restrict__ gamma) {
    int gid = blockIdx.x * 8 + (threadIdx.x >> 5);
    int lane = threadIdx.x & 31;
    int d = gid % kD;
    size_t idx = (size_t)gid * kG + lane;
    float v = X[idx] + gamma[d * kG + lane] * H[idx];
    float sq = v * v;
#pragma unroll
    for (int m = 16; m > 0; m >>= 1) sq += __shfl_xor(sq, m, 32);
    X[idx] = v / (sqrtf(sq) + 1e-6f);
}

// ---------------- scalar fp32 versor_linear, TRANSPOSED output --------------
// Kept fp32 (scan leaves are error-sensitive).  Writes DT[b][d][s][g] so each
// scan sequence is contiguous.
__global__ __launch_bounds__(256) void vlinT_kernel(const float* __restrict__ X,
                                                    const float* __restrict__ W,
                                                    const float* __restrict__ bias,
                                                    float* __restrict__ OutT) {
    __shared__ float sx[kDG];      // 8 KB
    __shared__ float sw[kD * kD];  // 16 KB
    int t = blockIdx.x, tid = threadIdx.x;
    const float* xp = X + (size_t)t * kDG;
    for (int j = tid; j < kDG; j += 256) sx[j] = xp[j];
    for (int j = tid; j < kD * kD; j += 256) sw[j] = W[j];
    __syncthreads();
    int g = tid & 31, ob = tid >> 5;
    int b = t >> 8, s = t & 255;
    float* op = OutT + ((size_t)b * kD * kS + s) * kG;   // + o*kS*kG + g
    for (int o = ob; o < kD; o += 8) {
        float acc = bias[o * kG + g];
        const float* wr = sw + o * kD;
#pragma unroll
        for (int i = 0; i < kD; i++) acc += wr[i] * sx[i * kG + g];
        op[(size_t)o * kS * kG + g] = acc;
    }
}

// ---------------- MFMA GEMM over (t,g) columns (Wo path / MLP1) -------------
template<int MT, bool MLP1OUT>
__global__ __launch_bounds__(256, 2) void gemm_tg_kernel(
    const float* __restrict__ X, const float* __restrict__ W,
    const float* __restrict__ bias, float* __restrict__ outF,
    unsigned short* __restrict__ outH) {
    constexpr int M = MT * 16;
    constexpr int WS = 64 + 8;                 // bf16 row stride
    __shared__ short sW[M * WS];
    __shared__ short sXT[4][32][WS];           // per-wave token, [g][i]

    const int tid = threadIdx.x, wave = tid >> 6, lane = tid & 63;
    const int l16 = lane & 15, quad = lane >> 4;
    const int tok = blockIdx.x * 4 + wave;

    for (int j = tid * 4; j < M * 64; j += 1024) {
        const float4 w4 = *(const float4*)(W + j);
        int o = j >> 6, i = j & 63;
        *(short4*)&sW[o * WS + i] = make_short4(f2bf(w4.x), f2bf(w4.y), f2bf(w4.z), f2bf(w4.w));
    }
    {
        const int g4 = (lane & 7) * 4;
        const int i0 = (lane >> 3) * 8;
        const float* xp = X + (size_t)tok * kDG;
#pragma unroll
        for (int half = 0; half < 2; ++half) {
            float4 vr[4];
#pragma unroll
            for (int r = 0; r < 4; ++r)
                vr[r] = *(const float4*)(xp + (i0 + half * 4 + r) * kG + g4);
#pragma unroll
            for (int gg = 0; gg < 4; ++gg)
                *(short4*)&sXT[wave][g4 + gg][i0 + half * 4] =
                    make_short4(f2bf((&vr[0].x)[gg]), f2bf((&vr[1].x)[gg]),
                                f2bf((&vr[2].x)[gg]), f2bf((&vr[3].x)[gg]));
        }
    }
    __syncthreads();

    bf16x8 bfr[2][2];
#pragma unroll
    for (int c = 0; c < 2; ++c)
#pragma unroll
        for (int nt = 0; nt < 2; ++nt)
            bfr[c][nt] = *(const bf16x8*)&sXT[wave][nt * 16 + l16][c * 32 + quad * 8];

    f32x4 acc[MT][2];
#pragma unroll
    for (int mt = 0; mt < MT; ++mt)
#pragma unroll
        for (int nt = 0; nt < 2; ++nt) acc[mt][nt] = (f32x4){0.f, 0.f, 0.f, 0.f};

#pragma unroll
    for (int mt = 0; mt < MT; ++mt)
#pragma unroll
        for (int c = 0; c < 2; ++c) {
            bf16x8 afr = *(const bf16x8*)&sW[(mt * 16 + l16) * WS + c * 32 + quad * 8];
#pragma unroll
            for (int nt = 0; nt < 2; ++nt)
                acc[mt][nt] = __builtin_amdgcn_mfma_f32_16x16x32_bf16(afr, bfr[c][nt], acc[mt][nt], 0, 0, 0);
        }

    if (!MLP1OUT) {
        float* op = outF + (size_t)tok * M * kG;
#pragma unroll
        for (int mt = 0; mt < MT; ++mt)
#pragma unroll
            for (int nt = 0; nt < 2; ++nt) {
                int g = nt * 16 + l16;
#pragma unroll
                for (int r = 0; r < 4; ++r) {
                    int o = mt * 16 + quad * 4 + r;
                    op[o * kG + g] = acc[mt][nt][r] + bias[o * kG + g];
                }
            }
    } else {
        unsigned short* op = outH + (size_t)tok * M * kG;   // [t][g][M]
#pragma unroll
        for (int mt = 0; mt < MT; ++mt)
#pragma unroll
            for (int nt = 0; nt < 2; ++nt) {
                int g = nt * 16 + l16;
                int e0 = mt * 16 + quad * 4;
                short4 s4;
                s4.x = f2bf(tanh_fast(acc[mt][nt][0] + bias[(e0 + 0) * kG + g]));
                s4.y = f2bf(tanh_fast(acc[mt][nt][1] + bias[(e0 + 1) * kG + g]));
                s4.z = f2bf(tanh_fast(acc[mt][nt][2] + bias[(e0 + 2) * kG + g]));
                s4.w = f2bf(tanh_fast(acc[mt][nt][3] + bias[(e0 + 3) * kG + g]));
                *(short4*)&op[g * M + e0] = s4;
            }
    }
}

// ---------------- fused Q/K/V GEMM (reads A once) ----------------
__global__ __launch_bounds__(256, 2) void gemm_qkv_kernel(
    const float* __restrict__ X,
    const float* __restrict__ Wq, const float* __restrict__ Wk, const float* __restrict__ Wv,
    const float* __restrict__ bq, const float* __restrict__ bk, const float* __restrict__ bv,
    float* __restrict__ Q, float* __restrict__ K, float* __restrict__ V) {
    constexpr int WS = 64 + 8;
    __shared__ short sW[3 * 64 * WS];          // 27.6 KB
    __shared__ short sXT[4][32][WS];           // 18.4 KB

    const int tid = threadIdx.x, wave = tid >> 6, lane = tid & 63;
    const int l16 = lane & 15, quad = lane >> 4;
    const int tok = blockIdx.x * 4 + wave;

    const float* Wp[3] = {Wq, Wk, Wv};
#pragma unroll
    for (int w = 0; w < 3; ++w)
        for (int j = tid * 4; j < 64 * 64; j += 1024) {
            const float4 w4 = *(const float4*)(Wp[w] + j);
            int o = j >> 6, i = j & 63;
            *(short4*)&sW[w * 64 * WS + o * WS + i] =
                make_short4(f2bf(w4.x), f2bf(w4.y), f2bf(w4.z), f2bf(w4.w));
        }
    {
        const int g4 = (lane & 7) * 4;
        const int i0 = (lane >> 3) * 8;
        const float* xp = X + (size_t)tok * kDG;
#pragma unroll
        for (int half = 0; half < 2; ++half) {
            float4 vr[4];
#pragma unroll
            for (int r = 0; r < 4; ++r)
                vr[r] = *(const float4*)(xp + (i0 + half * 4 + r) * kG + g4);
#pragma unroll
            for (int gg = 0; gg < 4; ++gg)
                *(short4*)&sXT[wave][g4 + gg][i0 + half * 4] =
                    make_short4(f2bf((&vr[0].x)[gg]), f2bf((&vr[1].x)[gg]),
                                f2bf((&vr[2].x)[gg]), f2bf((&vr[3].x)[gg]));
        }
    }
    __syncthreads();

    bf16x8 bfr[2][2];
#pragma unroll
    for (int c = 0; c < 2; ++c)
#pragma unroll
        for (int nt = 0; nt < 2; ++nt)
            bfr[c][nt] = *(const bf16x8*)&sXT[wave][nt * 16 + l16][c * 32 + quad * 8];

    f32x4 acc[3][4][2];
#pragma unroll
    for (int w = 0; w < 3; ++w)
#pragma unroll
        for (int mt = 0; mt < 4; ++mt)
#pragma unroll
            for (int nt = 0; nt < 2; ++nt) acc[w][mt][nt] = (f32x4){0.f, 0.f, 0.f, 0.f};

#pragma unroll
    for (int w = 0; w < 3; ++w)
#pragma unroll
        for (int mt = 0; mt < 4; ++mt)
#pragma unroll
            for (int c = 0; c < 2; ++c) {
                bf16x8 afr = *(const bf16x8*)&sW[w * 64 * WS + (mt * 16 + l16) * WS + c * 32 + quad * 8];
#pragma unroll
                for (int nt = 0; nt < 2; ++nt)
                    acc[w][mt][nt] = __builtin_amdgcn_mfma_f32_16x16x32_bf16(afr, bfr[c][nt], acc[w][mt][nt], 0, 0, 0);
            }

    float* Op[3] = {Q, K, V};
    const float* Bp[3] = {bq, bk, bv};
#pragma unroll
    for (int w = 0; w < 3; ++w) {
        float* op = Op[w] + (size_t)tok * kDG;
#pragma unroll
        for (int mt = 0; mt < 4; ++mt)
#pragma unroll
            for (int nt = 0; nt < 2; ++nt) {
                int g = nt * 16 + l16;
#pragma unroll
                for (int r = 0; r < 4; ++r) {
                    int o = mt * 16 + quad * 4 + r;
                    op[o * kG + g] = acc[w][mt][nt][r] + Bp[w][o * kG + g];
                }
            }
    }
}

// ---------------- MLP second half ----------------
__global__ __launch_bounds__(256, 2) void mlp2_kernel(
    const unsigned short* __restrict__ Mb,  // [t][32][256] bf16
    const float* __restrict__ W2,           // [64][256]
    const float* __restrict__ b2,           // [64][32]
    float* __restrict__ Out) {              // [t][64][32]
    constexpr int WS = 256 + 8;
    __shared__ short sW[64 * WS];
    const int tid = threadIdx.x, wave = tid >> 6, lane = tid & 63;
    const int l16 = lane & 15, quad = lane >> 4;
    const int tok = blockIdx.x * 4 + wave;

    for (int j = tid * 4; j < 64 * 256; j += 1024) {
        const float4 w4 = *(const float4*)(W2 + j);
        int o = j >> 8, i = j & 255;
        *(short4*)&sW[o * WS + i] = make_short4(f2bf(w4.x), f2bf(w4.y), f2bf(w4.z), f2bf(w4.w));
    }
    __syncthreads();

    f32x4 acc[4][2];
#pragma unroll
    for (int mt = 0; mt < 4; ++mt)
#pragma unroll
        for (int nt = 0; nt < 2; ++nt) acc[mt][nt] = (f32x4){0.f, 0.f, 0.f, 0.f};

    const unsigned short* mp = Mb + (size_t)tok * kG * kE;
#pragma unroll
    for (int c = 0; c < 8; ++c) {
        bf16x8 bfr[2];
#pragma unroll
        for (int nt = 0; nt < 2; ++nt)
            bfr[nt] = *(const bf16x8*)&mp[(nt * 16 + l16) * kE + c * 32 + quad * 8];
#pragma unroll
        for (int mt = 0; mt < 4; ++mt) {
            bf16x8 afr = *(const bf16x8*)&sW[(mt * 16 + l16) * WS + c * 32 + quad * 8];
#pragma unroll
            for (int nt = 0; nt < 2; ++nt)
                acc[mt][nt] = __builtin_amdgcn_mfma_f32_16x16x32_bf16(afr, bfr[nt], acc[mt][nt], 0, 0, 0);
        }
    }

    float* op = Out + (size_t)tok * kDG;
#pragma unroll
    for (int mt = 0; mt < 4; ++mt)
#pragma unroll
        for (int nt = 0; nt < 2; ++nt) {
            int g = nt * 16 + l16;
#pragma unroll
            for (int r = 0; r < 4; ++r) {
                int o = mt * 16 + quad * 4 + r;
                op[o * kG + g] = acc[mt][nt][r] + b2[o * kG + g];
            }
        }
}

// ---------------- MFMA flash-style attention ----------------
constexpr int QSTR = 264;
constexpr int VSTR = 40;

__global__ __launch_bounds__(256) void attn_mfma_kernel(const float* __restrict__ Q,
                                                        const float* __restrict__ K,
                                                        const float* __restrict__ V,
                                                        float* __restrict__ O) {
    __shared__ short sQ[64 * QSTR];
    __shared__ short sKV[256 * VSTR];

    const int qt = blockIdx.x, h = blockIdx.y, b = blockIdx.z;
    const int tid = threadIdx.x;
    const int wave = tid >> 6, lane = tid & 63;
    const int l16 = lane & 15, quad = lane >> 4;

    const size_t bh = (size_t)b * kS * kDG + (size_t)h * kHD;

    {
        int r0 = tid >> 6;
        int c4 = lane << 2;
        for (int it = 0; it < 16; ++it) {
            int row = it * 4 + r0;
            const float4 v = *(const float4*)(Q + bh + (size_t)(qt * 64 + row) * kDG + c4);
            short4 p = make_short4(f2bf(v.x), f2bf(v.y), f2bf(v.z), f2bf(v.w));
            *(short4*)&sQ[row * QSTR + c4] = p;
        }
    }
    __syncthreads();

    bf16x8 afrag[8];
    {
        int row = wave * 16 + l16;
#pragma unroll
        for (int c = 0; c < 8; ++c)
            afrag[c] = *(const bf16x8*)&sQ[row * QSTR + c * 32 + quad * 8];
    }

    f32x4 acc[16];
#pragma unroll
    for (int i = 0; i < 16; ++i) acc[i] = (f32x4){0.f, 0.f, 0.f, 0.f};

    for (int kt = 0; kt < 8; ++kt) {
        __syncthreads();
        {
            int r0 = tid >> 6;
            int c4 = lane << 2;
            for (int it = 0; it < 8; ++it) {
                int row = it * 4 + r0;
                const float4 v = *(const float4*)(K + bh + (size_t)(kt * 32 + row) * kDG + c4);
                short4 p = make_short4(f2bf(v.x), f2bf(v.y), f2bf(v.z), f2bf(v.w));
                *(short4*)&sKV[row * QSTR + c4] = p;
            }
        }
        __syncthreads();
#pragma unroll
        for (int nt = 0; nt < 2; ++nt) {
            int key = nt * 16 + l16;
            f32x4 a = acc[kt * 2 + nt];
#pragma unroll
            for (int c = 0; c < 8; ++c) {
                bf16x8 bfrag = *(const bf16x8*)&sKV[key * QSTR + c * 32 + quad * 8];
                a = __builtin_amdgcn_mfma_f32_16x16x32_bf16(afrag[c], bfrag, a, 0, 0, 0);
            }
            acc[kt * 2 + nt] = a;
        }
    }
    __syncthreads();

    float inv[4];
#pragma unroll
    for (int r = 0; r < 4; ++r) {
        float m = -1e30f;
#pragma unroll
        for (int t = 0; t < 16; ++t) m = fmaxf(m, acc[t][r]);
#pragma unroll
        for (int off = 1; off < 16; off <<= 1) m = fmaxf(m, __shfl_xor(m, off, 16));
        float s = 0.f;
#pragma unroll
        for (int t = 0; t < 16; ++t) {
            float p = __expf((acc[t][r] - m) * 0.0625f);
            acc[t][r] = p; s += p;
        }
#pragma unroll
        for (int off = 1; off < 16; off <<= 1) s += __shfl_xor(s, off, 16);
        inv[r] = 1.f / s;
    }

#pragma unroll
    for (int t = 0; t < 16; ++t)
#pragma unroll
        for (int r = 0; r < 4; ++r)
            sQ[(wave * 16 + quad * 4 + r) * QSTR + t * 16 + l16] = f2bf(acc[t][r]);

    f32x4 oacc[16];
#pragma unroll
    for (int i = 0; i < 16; ++i) oacc[i] = (f32x4){0.f, 0.f, 0.f, 0.f};

    for (int vt = 0; vt < 8; ++vt) {
        __syncthreads();
        {
            int kb = tid >> 5;
            for (int it = 0; it < 2; ++it) {
                int db = (tid & 31) + it * 32;
                float4 vr[4];
#pragma unroll
                for (int r = 0; r < 4; ++r)
                    vr[r] = *(const float4*)(V + bh + (size_t)(vt * 32 + kb * 4 + r) * kDG + db * 4);
#pragma unroll
                for (int i = 0; i < 4; ++i) {
                    short4 p = make_short4(f2bf((&vr[0].x)[i]), f2bf((&vr[1].x)[i]),
                                           f2bf((&vr[2].x)[i]), f2bf((&vr[3].x)[i]));
                    *(short4*)&sKV[(db * 4 + i) * VSTR + kb * 4] = p;
                }
            }
        }
        __syncthreads();
        bf16x8 pfrag = *(const bf16x8*)&sQ[(wave * 16 + l16) * QSTR + vt * 32 + quad * 8];
#pragma unroll
        for (int dt = 0; dt < 16; ++dt) {
            bf16x8 vfrag = *(const bf16x8*)&sKV[(dt * 16 + l16) * VSTR + quad * 8];
            oacc[dt] = __builtin_amdgcn_mfma_f32_16x16x32_bf16(pfrag, vfrag, oacc[dt], 0, 0, 0);
        }
    }

    {
        int qrow = qt * 64 + wave * 16 + quad * 4;
#pragma unroll
        for (int dt = 0; dt < 16; ++dt)
#pragma unroll
            for (int r = 0; r < 4; ++r)
                O[bh + (size_t)(qrow + r) * kDG + dt * 16 + l16] = oacc[dt][r] * inv[r];
    }
}

// ---------------- in-thread geometric product with compile-time signs -------
constexpr int pc_ce(unsigned v) { int c = 0; while (v) { c += v & 1; v >>= 1; } return c; }
constexpr unsigned gp_mask_ce(int a) {
    unsigned m = 0;
    for (int c = 0; c < 32; ++c) {
        int b = a ^ c;
        int s = (a & b) >> 4;                       // SIG[4] = -1 metric term
        for (int t = a >> 1; t; t >>= 1) s += pc_ce(t & b);
        if (s & 1) m |= (1u << c);
    }
    return m;
}

template<int A>
__device__ __forceinline__ void gp_term(const float* x, const float* y, float* acc) {
    constexpr unsigned m = gp_mask_ce(A);
    const float xa = x[A], nxa = -xa;
#pragma unroll
    for (int c = 0; c < 32; ++c)
        acc[c] = fmaf(((m >> c) & 1u) ? nxa : xa, y[A ^ c], acc[c]);
}

// out = mn(gp(x, y));  out may alias x or y (acc is local).
__device__ __forceinline__ void gp_mn_t(const float* x, const float* y, float* out) {
    float acc[32];
#pragma unroll
    for (int c = 0; c < 32; ++c) acc[c] = 0.f;
    gp_term<0>(x, y, acc);  gp_term<1>(x, y, acc);  gp_term<2>(x, y, acc);  gp_term<3>(x, y, acc);
    gp_term<4>(x, y, acc);  gp_term<5>(x, y, acc);  gp_term<6>(x, y, acc);  gp_term<7>(x, y, acc);
    gp_term<8>(x, y, acc);  gp_term<9>(x, y, acc);  gp_term<10>(x, y, acc); gp_term<11>(x, y, acc);
    gp_term<12>(x, y, acc); gp_term<13>(x, y, acc); gp_term<14>(x, y, acc); gp_term<15>(x, y, acc);
    gp_term<16>(x, y, acc); gp_term<17>(x, y, acc); gp_term<18>(x, y, acc); gp_term<19>(x, y, acc);
    gp_term<20>(x, y, acc); gp_term<21>(x, y, acc); gp_term<22>(x, y, acc); gp_term<23>(x, y, acc);
    gp_term<24>(x, y, acc); gp_term<25>(x, y, acc); gp_term<26>(x, y, acc); gp_term<27>(x, y, acc);
    gp_term<28>(x, y, acc); gp_term<29>(x, y, acc); gp_term<30>(x, y, acc); gp_term<31>(x, y, acc);
    float ss = 0.f;
#pragma unroll
    for (int c = 0; c < 32; ++c) ss = fmaf(acc[c], acc[c], ss);
    float r = 1.f / (sqrtf(ss) + 1e-6f);
#pragma unroll
    for (int c = 0; c < 32; ++c) out[c] = acc[c] * r;
}

// load leaf p (32 floats) and rotinit: v = mn(0.5*raw + e0)
__device__ __forceinline__ void leaf_load(const float* base, float* v) {
#pragma unroll
    for (int i = 0; i < 8; ++i) {
        const float4 f = *(const float4*)(base + i * 4);
        v[i * 4 + 0] = 0.5f * f.x; v[i * 4 + 1] = 0.5f * f.y;
        v[i * 4 + 2] = 0.5f * f.z; v[i * 4 + 3] = 0.5f * f.w;
    }
    v[0] += 1.f;
    float ss = 0.f;
#pragma unroll
    for (int c = 0; c < 32; ++c) ss = fmaf(v[c], v[c], ss);
    float r = 1.f / (sqrtf(ss) + 1e-6f);
#pragma unroll
    for (int c = 0; c < 32; ++c) v[c] *= r;
}

// ---------------- scan: wave per sequence, rotor per thread -----------------
// DT layout [b][d][s][g] (sequence-contiguous).  Lane l folds leaves
// 4l..4l+3 in registers (3 gp nodes, zero LDS), then 6 shfl_xor butterfly
// levels; all lanes compute both sides -> no divergence, no barriers.
// Association differs from the reference scan but the pooled direction is
// association-independent (gp associative; mn = positive rescale).
__global__ __launch_bounds__(256) void scanreg_kernel(const float* __restrict__ DT,
                                                      float* __restrict__ pooled) {
    const int wave = threadIdx.x >> 6, lane = threadIdx.x & 63;
    const int seq = blockIdx.x * 4 + wave;               // b*64 + d
    const float* base = DT + ((size_t)seq * kS + lane * 4) * kG;

    float R[32], Y[32], P[32], Xa[32], Yb[32];

    leaf_load(base, R);
    for (int j = 1; j < 4; ++j) {
        leaf_load(base + j * kG, Y);
        gp_mn_t(Y, R, R);                                // later ∘ earlier
    }

    for (int step = 1; step < 64; step <<= 1) {
        const bool up = lane & step;                     // own range is the later half
#pragma unroll
        for (int c = 0; c < 32; ++c) P[c] = __shfl_xor(R[c], step, 64);
#pragma unroll
        for (int c = 0; c < 32; ++c) {
            Xa[c] = up ? R[c] : P[c];                    // later operand
            Yb[c] = up ? P[c] : R[c];                    // earlier operand
        }
        gp_mn_t(Xa, Yb, R);
    }

    if (lane == 0) {
        float* op = pooled + (size_t)seq * kG;
#pragma unroll
        for (int i = 0; i < 8; ++i)
            *(float4*)(op + i * 4) = make_float4(R[i * 4], R[i * 4 + 1], R[i * 4 + 2], R[i * 4 + 3]);
    }
}

// ---------------- classifier: wave per class, pooled staged in LDS ----------
__global__ __launch_bounds__(256) void cls2_kernel(const float* __restrict__ P,   // [8][2048]
                                                   const float* __restrict__ Wc,
                                                   const float* __restrict__ bc,
                                                   float* __restrict__ out) {
    __shared__ float sp[kB * kDG];   // 64 KB
    const int tid = threadIdx.x, wave = tid >> 6, lane = tid & 63;
    for (int j = tid * 4; j < kB * kDG; j += 1024)
        *(float4*)&sp[j] = *(const float4*)(P + j);
    __syncthreads();

    const int c = blockIdx.x * 4 + wave;
    const float* w = Wc + (size_t)c * kDG;
    float acc[kB];
#pragma unroll
    for (int b = 0; b < kB; ++b) acc[b] = 0.f;
#pragma unroll
    for (int cc = 0; cc < 8; ++cc) {
        const float4 w4 = *(const float4*)(w + cc * 256 + lane * 4);
#pragma unroll
        for (int b = 0; b < kB; ++b) {
            const float4 p4 = *(const float4*)&sp[b * kDG + cc * 256 + lane * 4];
            acc[b] += w4.x * p4.x + w4.y * p4.y + w4.z * p4.z + w4.w * p4.w;
        }
    }
#pragma unroll
    for (int b = 0; b < kB; ++b)
#pragma unroll
        for (int off = 32; off > 0; off >>= 1) acc[b] += __shfl_xor(acc[b], off, 64);
    if (lane == 0) {
        float bias = bc[c];
#pragma unroll
        for (int b = 0; b < kB; ++b) out[b * kNC + c] = acc[b] + bias;
    }
}

extern "C" void kernel_launch(void* const* d_in, const int* in_sizes, int n_in,
                              void* d_out, int out_size, void* d_ws, size_t ws_size,
                              hipStream_t stream) {
    const float* x_in = (const float*)d_in[0];
    const float* Wq   = (const float*)d_in[1];
    const float* bq   = (const float*)d_in[2];
    const float* Wk   = (const float*)d_in[3];
    const float* bk   = (const float*)d_in[4];
    const float* Wv   = (const float*)d_in[5];
    const float* bv   = (const float*)d_in[6];
    const float* Wo   = (const float*)d_in[7];
    const float* bo   = (const float*)d_in[8];
    const float* ln1w = (const float*)d_in[9];
    const float* ln1b = (const float*)d_in[10];
    const float* ln2w = (const float*)d_in[11];
    const float* ln2b = (const float*)d_in[12];
    const float* gm1  = (const float*)d_in[13];
    const float* gm2  = (const float*)d_in[14];
    const float* W1   = (const float*)d_in[15];
    const float* b1   = (const float*)d_in[16];
    const float* W2   = (const float*)d_in[17];
    const float* b2   = (const float*)d_in[18];
    const float* Wr   = (const float*)d_in[19];
    const float* br   = (const float*)d_in[20];
    const float* Wc   = (const float*)d_in[21];
    const float* bc   = (const float*)d_in[22];

    const size_t NEL = (size_t)kT * kDG;
    float* F  = (float*)d_ws;
    float* X  = F;
    float* A  = F + NEL;
    float* Qb = F + 2 * NEL;
    float* Kb = F + 3 * NEL;
    float* Vb = F + 4 * NEL;
    unsigned short* Mb = (unsigned short*)Kb;   // bf16 [t][32][256], reuses Kb+Vb
    float* pooled = Qb;                         // 16K floats, Qb free at scan time

    ln_kernel<<<kT, 256, 0, stream>>>(x_in, ln1w, ln1b, A);

    for (int l = 0; l < 4; l++) {
        gemm_qkv_kernel<<<kT / 4, 256, 0, stream>>>(A,
            Wq + l * kD * kD, Wk + l * kD * kD, Wv + l * kD * kD,
            bq + l * kDG, bk + l * kDG, bv + l * kDG, Qb, Kb, Vb);
        attn_mfma_kernel<<<dim3(4, kNH, kB), 256, 0, stream>>>(Qb, Kb, Vb, A);
        gemm_tg_kernel<4, false><<<kT / 4, 256, 0, stream>>>(A, Wo + l * kD * kD, bo + l * kDG, Qb, nullptr);
        resmn_ln_kernel<<<kT, 256, 0, stream>>>(l == 0 ? x_in : X, X, Qb,
            gm1 + l * kDG, ln2w + l * kDG, ln2b + l * kDG, A);
        gemm_tg_kernel<16, true><<<kT / 4, 256, 0, stream>>>(A, W1 + l * kE * kD, b1 + l * kE * kG, nullptr, Mb);
        mlp2_kernel<<<kT / 4, 256, 0, stream>>>(Mb, W2 + l * kD * kE, b2 + l * kDG, Qb);
        if (l < 3)
            resmn_ln_kernel<<<kT, 256, 0, stream>>>(X, X, Qb, gm2 + l * kDG,
                ln1w + (l + 1) * kDG, ln1b + (l + 1) * kDG, A);
        else
            resmn_kernel<<<kT * kD / 8, 256, 0, stream>>>(X, Qb, gm2 + l * kDG);
    }

    // delta (fp32, transposed layout) -> register-resident reduction -> classifier
    vlinT_kernel<<<kT, 256, 0, stream>>>(X, Wr, br, A);
    scanreg_kernel<<<kB * kD / 4, 256, 0, stream>>>(A, pooled);
    cls2_kernel<<<kNC / 4, 256, 0, stream>>>(pooled, Wc, bc, (float*)d_out);
}

// Round 9
// 610.638 us; speedup vs baseline: 1.2727x; 1.0765x over previous
//
#include <hip/hip_runtime.h>
#include <hip/hip_bf16.h>

// Problem constants (B=8, S=256, D=64, G=32, E=256, L=4, NH=8, DH=8)
constexpr int kB  = 8;
constexpr int kS  = 256;
constexpr int kD  = 64;
constexpr int kG  = 32;
constexpr int kE  = 256;
constexpr int kNH = 8;
constexpr int kHD = 256;              // DH*G = 8*32
constexpr int kDG = kD * kG;          // 2048
constexpr int kT  = kB * kS;          // 2048 tokens
constexpr int kNC = 1000;

using bf16x8 = __attribute__((ext_vector_type(8))) short;
using f32x4  = __attribute__((ext_vector_type(4))) float;

__device__ __forceinline__ short f2bf(float f) {
    unsigned u = __float_as_uint(f);
    unsigned r = (u + 0x7FFFu + ((u >> 16) & 1u)) >> 16;   // RNE
    return (short)r;
}

__device__ __forceinline__ float tanh_fast(float x) {
    float a = fabsf(x);
    float e = __expf(-2.f * a);
    float t = (1.f - e) / (1.f + e);
    return copysignf(t, x);
}

// ---------------- LN of x_in (layer 0) ----------------
__global__ __launch_bounds__(256) void ln_kernel(const float* __restrict__ Xin,
                                                 const float* __restrict__ w,
                                                 const float* __restrict__ b,
                                                 float* __restrict__ A) {
    int t = blockIdx.x, tid = threadIdx.x;
    const float* xp = Xin + (size_t)t * kDG;
    __shared__ float r1[256], r2[256];
    float v[8], s = 0.f, ss = 0.f;
#pragma unroll
    for (int j = 0; j < 8; j++) {
        float x = xp[tid + j * 256];
        v[j] = x; s += x; ss += x * x;
    }
    r1[tid] = s; r2[tid] = ss; __syncthreads();
    for (int o = 128; o > 0; o >>= 1) {
        if (tid < o) { r1[tid] += r1[tid + o]; r2[tid] += r2[tid + o]; }
        __syncthreads();
    }
    float mean = r1[0] * (1.f / kDG);
    float var  = r2[0] * (1.f / kDG) - mean * mean;
    float rstd = rsqrtf(var + 1e-5f);
    float* ao = A + (size_t)t * kDG;
#pragma unroll
    for (int j = 0; j < 8; j++) {
        int jj = tid + j * 256;
        ao[jj] = (v[j] - mean) * rstd * w[jj] + b[jj];
    }
}

// ---------------- fused epilogue: residual + mn + (optional) next LN -------
// Wave holds full token output in acc[4][2] (o = mt*16+quad*4+r, g = nt*16+l16).
// mn over g: 16-lane xor reduce; LN over token: 64-lane xor reduce.
__device__ __forceinline__ void epi_res_mn_ln(
    const f32x4 (&acc)[4][2], const float* __restrict__ bias,
    const float* __restrict__ Xin, float* __restrict__ Xout,
    const float* __restrict__ gamma,
    const float* __restrict__ lnw, const float* __restrict__ lnb,
    float* __restrict__ Aout, int tok, int l16, int quad, bool do_ln) {
    const size_t tb = (size_t)tok * kDG;
    float xv[4][2][4];
    float s = 0.f, ss = 0.f;
#pragma unroll
    for (int mt = 0; mt < 4; ++mt)
#pragma unroll
        for (int r = 0; r < 4; ++r) {
            int o = mt * 16 + quad * 4 + r;
            float vv[2]; float sq = 0.f;
#pragma unroll
            for (int nt = 0; nt < 2; ++nt) {
                int g = nt * 16 + l16;
                float h = acc[mt][nt][r] + bias[o * kG + g];
                float v = Xin[tb + o * kG + g] + gamma[o * kG + g] * h;
                vv[nt] = v; sq = fmaf(v, v, sq);
            }
#pragma unroll
            for (int off = 1; off < 16; off <<= 1) sq += __shfl_xor(sq, off, 64);
            float rn = 1.f / (sqrtf(sq) + 1e-6f);
#pragma unroll
            for (int nt = 0; nt < 2; ++nt) {
                int g = nt * 16 + l16;
                float x = vv[nt] * rn;
                xv[mt][nt][r] = x;
                Xout[tb + o * kG + g] = x;
                s += x; ss = fmaf(x, x, ss);
            }
        }
    if (!do_ln) return;
#pragma unroll
    for (int off = 1; off < 64; off <<= 1) {
        s += __shfl_xor(s, off, 64); ss += __shfl_xor(ss, off, 64);
    }
    float mean = s * (1.f / kDG);
    float var  = ss * (1.f / kDG) - mean * mean;
    float rstd = rsqrtf(var + 1e-5f);
#pragma unroll
    for (int mt = 0; mt < 4; ++mt)
#pragma unroll
        for (int nt = 0; nt < 2; ++nt) {
            int g = nt * 16 + l16;
#pragma unroll
            for (int r = 0; r < 4; ++r) {
                int o = mt * 16 + quad * 4 + r;
                Aout[tb + o * kG + g] = (xv[mt][nt][r] - mean) * rstd * lnw[o * kG + g] + lnb[o * kG + g];
            }
        }
}

// ---------------- scalar fp32 versor_linear, TRANSPOSED output --------------
// Kept fp32 (scan leaves are error-sensitive).  Writes DT[b][d][s][g].
__global__ __launch_bounds__(256) void vlinT_kernel(const float* __restrict__ X,
                                                    const float* __restrict__ W,
                                                    const float* __restrict__ bias,
                                                    float* __restrict__ OutT) {
    __shared__ float sx[kDG];      // 8 KB
    __shared__ float sw[kD * kD];  // 16 KB
    int t = blockIdx.x, tid = threadIdx.x;
    const float* xp = X + (size_t)t * kDG;
    for (int j = tid; j < kDG; j += 256) sx[j] = xp[j];
    for (int j = tid; j < kD * kD; j += 256) sw[j] = W[j];
    __syncthreads();
    int g = tid & 31, ob = tid >> 5;
    int b = t >> 8, s = t & 255;
    float* op = OutT + ((size_t)b * kD * kS + s) * kG;
    for (int o = ob; o < kD; o += 8) {
        float acc = bias[o * kG + g];
        const float* wr = sw + o * kD;
#pragma unroll
        for (int i = 0; i < kD; i++) acc += wr[i] * sx[i * kG + g];
        op[(size_t)o * kS * kG + g] = acc;
    }
}

// ---------------- MLP1 GEMM (M=256, tanh, bf16 [t][g][e] out) --------------
__global__ __launch_bounds__(256, 2) void mlp1_kernel(
    const float* __restrict__ X, const float* __restrict__ W,
    const float* __restrict__ bias, unsigned short* __restrict__ outH) {
    constexpr int M = 256;
    constexpr int WS = 64 + 8;
    __shared__ short sW[M * WS];
    __shared__ short sXT[4][32][WS];

    const int tid = threadIdx.x, wave = tid >> 6, lane = tid & 63;
    const int l16 = lane & 15, quad = lane >> 4;
    const int tok = blockIdx.x * 4 + wave;

    for (int j = tid * 4; j < M * 64; j += 1024) {
        const float4 w4 = *(const float4*)(W + j);
        int o = j >> 6, i = j & 63;
        *(short4*)&sW[o * WS + i] = make_short4(f2bf(w4.x), f2bf(w4.y), f2bf(w4.z), f2bf(w4.w));
    }
    {
        const int g4 = (lane & 7) * 4;
        const int i0 = (lane >> 3) * 8;
        const float* xp = X + (size_t)tok * kDG;
#pragma unroll
        for (int half = 0; half < 2; ++half) {
            float4 vr[4];
#pragma unroll
            for (int r = 0; r < 4; ++r)
                vr[r] = *(const float4*)(xp + (i0 + half * 4 + r) * kG + g4);
#pragma unroll
            for (int gg = 0; gg < 4; ++gg)
                *(short4*)&sXT[wave][g4 + gg][i0 + half * 4] =
                    make_short4(f2bf((&vr[0].x)[gg]), f2bf((&vr[1].x)[gg]),
                                f2bf((&vr[2].x)[gg]), f2bf((&vr[3].x)[gg]));
        }
    }
    __syncthreads();

    bf16x8 bfr[2][2];
#pragma unroll
    for (int c = 0; c < 2; ++c)
#pragma unroll
        for (int nt = 0; nt < 2; ++nt)
            bfr[c][nt] = *(const bf16x8*)&sXT[wave][nt * 16 + l16][c * 32 + quad * 8];

    f32x4 acc[16][2];
#pragma unroll
    for (int mt = 0; mt < 16; ++mt)
#pragma unroll
        for (int nt = 0; nt < 2; ++nt) acc[mt][nt] = (f32x4){0.f, 0.f, 0.f, 0.f};

#pragma unroll
    for (int mt = 0; mt < 16; ++mt)
#pragma unroll
        for (int c = 0; c < 2; ++c) {
            bf16x8 afr = *(const bf16x8*)&sW[(mt * 16 + l16) * WS + c * 32 + quad * 8];
#pragma unroll
            for (int nt = 0; nt < 2; ++nt)
                acc[mt][nt] = __builtin_amdgcn_mfma_f32_16x16x32_bf16(afr, bfr[c][nt], acc[mt][nt], 0, 0, 0);
        }

    unsigned short* op = outH + (size_t)tok * M * kG;   // [t][g][M]
#pragma unroll
    for (int mt = 0; mt < 16; ++mt)
#pragma unroll
        for (int nt = 0; nt < 2; ++nt) {
            int g = nt * 16 + l16;
            int e0 = mt * 16 + quad * 4;
            short4 s4;
            s4.x = f2bf(tanh_fast(acc[mt][nt][0] + bias[(e0 + 0) * kG + g]));
            s4.y = f2bf(tanh_fast(acc[mt][nt][1] + bias[(e0 + 1) * kG + g]));
            s4.z = f2bf(tanh_fast(acc[mt][nt][2] + bias[(e0 + 2) * kG + g]));
            s4.w = f2bf(tanh_fast(acc[mt][nt][3] + bias[(e0 + 3) * kG + g]));
            *(short4*)&op[g * M + e0] = s4;
        }
}

// ---------------- Wo GEMM with fused residual+mn+LN2 epilogue ---------------
__global__ __launch_bounds__(256, 2) void gemmWo_fused_kernel(
    const float* __restrict__ X, const float* __restrict__ W,
    const float* __restrict__ bias,
    const float* __restrict__ Xin, const float* __restrict__ gamma,
    const float* __restrict__ lnw, const float* __restrict__ lnb,
    float* __restrict__ Xout, float* __restrict__ Aout) {
    constexpr int WS = 64 + 8;
    __shared__ short sW[64 * WS];
    __shared__ short sXT[4][32][WS];

    const int tid = threadIdx.x, wave = tid >> 6, lane = tid & 63;
    const int l16 = lane & 15, quad = lane >> 4;
    const int tok = blockIdx.x * 4 + wave;

    for (int j = tid * 4; j < 64 * 64; j += 1024) {
        const float4 w4 = *(const float4*)(W + j);
        int o = j >> 6, i = j & 63;
        *(short4*)&sW[o * WS + i] = make_short4(f2bf(w4.x), f2bf(w4.y), f2bf(w4.z), f2bf(w4.w));
    }
    {
        const int g4 = (lane & 7) * 4;
        const int i0 = (lane >> 3) * 8;
        const float* xp = X + (size_t)tok * kDG;
#pragma unroll
        for (int half = 0; half < 2; ++half) {
            float4 vr[4];
#pragma unroll
            for (int r = 0; r < 4; ++r)
                vr[r] = *(const float4*)(xp + (i0 + half * 4 + r) * kG + g4);
#pragma unroll
            for (int gg = 0; gg < 4; ++gg)
                *(short4*)&sXT[wave][g4 + gg][i0 + half * 4] =
                    make_short4(f2bf((&vr[0].x)[gg]), f2bf((&vr[1].x)[gg]),
                                f2bf((&vr[2].x)[gg]), f2bf((&vr[3].x)[gg]));
        }
    }
    __syncthreads();

    bf16x8 bfr[2][2];
#pragma unroll
    for (int c = 0; c < 2; ++c)
#pragma unroll
        for (int nt = 0; nt < 2; ++nt)
            bfr[c][nt] = *(const bf16x8*)&sXT[wave][nt * 16 + l16][c * 32 + quad * 8];

    f32x4 acc[4][2];
#pragma unroll
    for (int mt = 0; mt < 4; ++mt)
#pragma unroll
        for (int nt = 0; nt < 2; ++nt) acc[mt][nt] = (f32x4){0.f, 0.f, 0.f, 0.f};

#pragma unroll
    for (int mt = 0; mt < 4; ++mt)
#pragma unroll
        for (int c = 0; c < 2; ++c) {
            bf16x8 afr = *(const bf16x8*)&sW[(mt * 16 + l16) * WS + c * 32 + quad * 8];
#pragma unroll
            for (int nt = 0; nt < 2; ++nt)
                acc[mt][nt] = __builtin_amdgcn_mfma_f32_16x16x32_bf16(afr, bfr[c][nt], acc[mt][nt], 0, 0, 0);
        }

    epi_res_mn_ln(acc, bias, Xin, Xout, gamma, lnw, lnb, Aout, tok, l16, quad, true);
}

// ---------------- fused Q/K/V GEMM -> bf16 outputs ----------------
__global__ __launch_bounds__(256, 2) void gemm_qkv_kernel(
    const float* __restrict__ X,
    const float* __restrict__ Wq, const float* __restrict__ Wk, const float* __restrict__ Wv,
    const float* __restrict__ bq, const float* __restrict__ bk, const float* __restrict__ bv,
    unsigned short* __restrict__ Q, unsigned short* __restrict__ K, unsigned short* __restrict__ V) {
    constexpr int WS = 64 + 8;
    __shared__ short sW[3 * 64 * WS];
    __shared__ short sXT[4][32][WS];

    const int tid = threadIdx.x, wave = tid >> 6, lane = tid & 63;
    const int l16 = lane & 15, quad = lane >> 4;
    const int tok = blockIdx.x * 4 + wave;

    const float* Wp[3] = {Wq, Wk, Wv};
#pragma unroll
    for (int w = 0; w < 3; ++w)
        for (int j = tid * 4; j < 64 * 64; j += 1024) {
            const float4 w4 = *(const float4*)(Wp[w] + j);
            int o = j >> 6, i = j & 63;
            *(short4*)&sW[w * 64 * WS + o * WS + i] =
                make_short4(f2bf(w4.x), f2bf(w4.y), f2bf(w4.z), f2bf(w4.w));
        }
    {
        const int g4 = (lane & 7) * 4;
        const int i0 = (lane >> 3) * 8;
        const float* xp = X + (size_t)tok * kDG;
#pragma unroll
        for (int half = 0; half < 2; ++half) {
            float4 vr[4];
#pragma unroll
            for (int r = 0; r < 4; ++r)
                vr[r] = *(const float4*)(xp + (i0 + half * 4 + r) * kG + g4);
#pragma unroll
            for (int gg = 0; gg < 4; ++gg)
                *(short4*)&sXT[wave][g4 + gg][i0 + half * 4] =
                    make_short4(f2bf((&vr[0].x)[gg]), f2bf((&vr[1].x)[gg]),
                                f2bf((&vr[2].x)[gg]), f2bf((&vr[3].x)[gg]));
        }
    }
    __syncthreads();

    bf16x8 bfr[2][2];
#pragma unroll
    for (int c = 0; c < 2; ++c)
#pragma unroll
        for (int nt = 0; nt < 2; ++nt)
            bfr[c][nt] = *(const bf16x8*)&sXT[wave][nt * 16 + l16][c * 32 + quad * 8];

    f32x4 acc[3][4][2];
#pragma unroll
    for (int w = 0; w < 3; ++w)
#pragma unroll
        for (int mt = 0; mt < 4; ++mt)
#pragma unroll
            for (int nt = 0; nt < 2; ++nt) acc[w][mt][nt] = (f32x4){0.f, 0.f, 0.f, 0.f};

#pragma unroll
    for (int w = 0; w < 3; ++w)
#pragma unroll
        for (int mt = 0; mt < 4; ++mt)
#pragma unroll
            for (int c = 0; c < 2; ++c) {
                bf16x8 afr = *(const bf16x8*)&sW[w * 64 * WS + (mt * 16 + l16) * WS + c * 32 + quad * 8];
#pragma unroll
                for (int nt = 0; nt < 2; ++nt)
                    acc[w][mt][nt] = __builtin_amdgcn_mfma_f32_16x16x32_bf16(afr, bfr[c][nt], acc[w][mt][nt], 0, 0, 0);
            }

    unsigned short* Op[3] = {Q, K, V};
    const float* Bp[3] = {bq, bk, bv};
#pragma unroll
    for (int w = 0; w < 3; ++w) {
        unsigned short* op = Op[w] + (size_t)tok * kDG;
#pragma unroll
        for (int mt = 0; mt < 4; ++mt)
#pragma unroll
            for (int nt = 0; nt < 2; ++nt) {
                int g = nt * 16 + l16;
#pragma unroll
                for (int r = 0; r < 4; ++r) {
                    int o = mt * 16 + quad * 4 + r;
                    op[o * kG + g] = (unsigned short)f2bf(acc[w][mt][nt][r] + Bp[w][o * kG + g]);
                }
            }
    }
}

// ---------------- MLP2 GEMM with fused residual+mn+(LN1 next) epilogue -----
template<bool DO_LN>
__global__ __launch_bounds__(256, 2) void mlp2_fused_kernel(
    const unsigned short* __restrict__ Mb,  // [t][32][256] bf16
    const float* __restrict__ W2, const float* __restrict__ b2,
    float* __restrict__ X, const float* __restrict__ gamma,
    const float* __restrict__ lnw, const float* __restrict__ lnb,
    float* __restrict__ Aout) {
    constexpr int WS = 256 + 8;
    __shared__ short sW[64 * WS];
    const int tid = threadIdx.x, wave = tid >> 6, lane = tid & 63;
    const int l16 = lane & 15, quad = lane >> 4;
    const int tok = blockIdx.x * 4 + wave;

    for (int j = tid * 4; j < 64 * 256; j += 1024) {
        const float4 w4 = *(const float4*)(W2 + j);
        int o = j >> 8, i = j & 255;
        *(short4*)&sW[o * WS + i] = make_short4(f2bf(w4.x), f2bf(w4.y), f2bf(w4.z), f2bf(w4.w));
    }
    __syncthreads();

    f32x4 acc[4][2];
#pragma unroll
    for (int mt = 0; mt < 4; ++mt)
#pragma unroll
        for (int nt = 0; nt < 2; ++nt) acc[mt][nt] = (f32x4){0.f, 0.f, 0.f, 0.f};

    const unsigned short* mp = Mb + (size_t)tok * kG * kE;
#pragma unroll
    for (int c = 0; c < 8; ++c) {
        bf16x8 bfr[2];
#pragma unroll
        for (int nt = 0; nt < 2; ++nt)
            bfr[nt] = *(const bf16x8*)&mp[(nt * 16 + l16) * kE + c * 32 + quad * 8];
#pragma unroll
        for (int mt = 0; mt < 4; ++mt) {
            bf16x8 afr = *(const bf16x8*)&sW[(mt * 16 + l16) * WS + c * 32 + quad * 8];
#pragma unroll
            for (int nt = 0; nt < 2; ++nt)
                acc[mt][nt] = __builtin_amdgcn_mfma_f32_16x16x32_bf16(afr, bfr[nt], acc[mt][nt], 0, 0, 0);
        }
    }

    epi_res_mn_ln(acc, b2, X, X, gamma, lnw, lnb, Aout, tok, l16, quad, DO_LN);
}

// ---------------- MFMA flash-style attention (bf16 Q/K/V inputs) -----------
constexpr int QSTR = 264;
constexpr int VSTR = 40;

__global__ __launch_bounds__(256) void attn_mfma_kernel(const unsigned short* __restrict__ Q,
                                                        const unsigned short* __restrict__ K,
                                                        const unsigned short* __restrict__ V,
                                                        float* __restrict__ O) {
    __shared__ short sQ[64 * QSTR];
    __shared__ short sKV[256 * VSTR];

    const int qt = blockIdx.x, h = blockIdx.y, b = blockIdx.z;
    const int tid = threadIdx.x;
    const int wave = tid >> 6, lane = tid & 63;
    const int l16 = lane & 15, quad = lane >> 4;

    const size_t bh = (size_t)b * kS * kDG + (size_t)h * kHD;

    // stage Q tile (bf16 direct, 16B loads)
#pragma unroll
    for (int it = 0; it < 8; ++it) {
        int j = it * 2048 + tid * 8;
        int row = j >> 8, col = j & 255;
        *(bf16x8*)&sQ[row * QSTR + col] =
            *(const bf16x8*)(Q + bh + (size_t)(qt * 64 + row) * kDG + col);
    }
    __syncthreads();

    bf16x8 afrag[8];
    {
        int row = wave * 16 + l16;
#pragma unroll
        for (int c = 0; c < 8; ++c)
            afrag[c] = *(const bf16x8*)&sQ[row * QSTR + c * 32 + quad * 8];
    }

    f32x4 acc[16];
#pragma unroll
    for (int i = 0; i < 16; ++i) acc[i] = (f32x4){0.f, 0.f, 0.f, 0.f};

    for (int kt = 0; kt < 8; ++kt) {
        __syncthreads();
#pragma unroll
        for (int it = 0; it < 4; ++it) {
            int j = it * 2048 + tid * 8;
            int row = j >> 8, col = j & 255;
            *(bf16x8*)&sKV[row * QSTR + col] =
                *(const bf16x8*)(K + bh + (size_t)(kt * 32 + row) * kDG + col);
        }
        __syncthreads();
#pragma unroll
        for (int nt = 0; nt < 2; ++nt) {
            int key = nt * 16 + l16;
            f32x4 a = acc[kt * 2 + nt];
#pragma unroll
            for (int c = 0; c < 8; ++c) {
                bf16x8 bfrag = *(const bf16x8*)&sKV[key * QSTR + c * 32 + quad * 8];
                a = __builtin_amdgcn_mfma_f32_16x16x32_bf16(afrag[c], bfrag, a, 0, 0, 0);
            }
            acc[kt * 2 + nt] = a;
        }
    }
    __syncthreads();

    float inv[4];
#pragma unroll
    for (int r = 0; r < 4; ++r) {
        float m = -1e30f;
#pragma unroll
        for (int t = 0; t < 16; ++t) m = fmaxf(m, acc[t][r]);
#pragma unroll
        for (int off = 1; off < 16; off <<= 1) m = fmaxf(m, __shfl_xor(m, off, 16));
        float s = 0.f;
#pragma unroll
        for (int t = 0; t < 16; ++t) {
            float p = __expf((acc[t][r] - m) * 0.0625f);
            acc[t][r] = p; s += p;
        }
#pragma unroll
        for (int off = 1; off < 16; off <<= 1) s += __shfl_xor(s, off, 16);
        inv[r] = 1.f / s;
    }

#pragma unroll
    for (int t = 0; t < 16; ++t)
#pragma unroll
        for (int r = 0; r < 4; ++r)
            sQ[(wave * 16 + quad * 4 + r) * QSTR + t * 16 + l16] = f2bf(acc[t][r]);

    f32x4 oacc[16];
#pragma unroll
    for (int i = 0; i < 16; ++i) oacc[i] = (f32x4){0.f, 0.f, 0.f, 0.f};

    for (int vt = 0; vt < 8; ++vt) {
        __syncthreads();
        {
            int kb = tid >> 5;
#pragma unroll
            for (int it = 0; it < 2; ++it) {
                int db = (tid & 31) + it * 32;
                short4 vr[4];
#pragma unroll
                for (int r = 0; r < 4; ++r)
                    vr[r] = *(const short4*)(V + bh + (size_t)(vt * 32 + kb * 4 + r) * kDG + db * 4);
#pragma unroll
                for (int i = 0; i < 4; ++i) {
                    short4 p = make_short4((&vr[0].x)[i], (&vr[1].x)[i],
                                           (&vr[2].x)[i], (&vr[3].x)[i]);
                    *(short4*)&sKV[(db * 4 + i) * VSTR + kb * 4] = p;
                }
            }
        }
        __syncthreads();
        bf16x8 pfrag = *(const bf16x8*)&sQ[(wave * 16 + l16) * QSTR + vt * 32 + quad * 8];
#pragma unroll
        for (int dt = 0; dt < 16; ++dt) {
            bf16x8 vfrag = *(const bf16x8*)&sKV[(dt * 16 + l16) * VSTR + quad * 8];
            oacc[dt] = __builtin_amdgcn_mfma_f32_16x16x32_bf16(pfrag, vfrag, oacc[dt], 0, 0, 0);
        }
    }

    {
        int qrow = qt * 64 + wave * 16 + quad * 4;
#pragma unroll
        for (int dt = 0; dt < 16; ++dt)
#pragma unroll
            for (int r = 0; r < 4; ++r)
                O[bh + (size_t)(qrow + r) * kDG + dt * 16 + l16] = oacc[dt][r] * inv[r];
    }
}

// ---------------- in-thread geometric product with compile-time signs -------
constexpr int pc_ce(unsigned v) { int c = 0; while (v) { c += v & 1; v >>= 1; } return c; }
constexpr unsigned gp_mask_ce(int a) {
    unsigned m = 0;
    for (int c = 0; c < 32; ++c) {
        int b = a ^ c;
        int s = (a & b) >> 4;                       // SIG[4] = -1 metric term
        for (int t = a >> 1; t; t >>= 1) s += pc_ce(t & b);
        if (s & 1) m |= (1u << c);
    }
    return m;
}

template<int A>
__device__ __forceinline__ void gp_term(const float* x, const float* y, float* acc) {
    constexpr unsigned m = gp_mask_ce(A);
    const float xa = x[A], nxa = -xa;
#pragma unroll
    for (int c = 0; c < 32; ++c)
        acc[c] = fmaf(((m >> c) & 1u) ? nxa : xa, y[A ^ c], acc[c]);
}

__device__ __forceinline__ void gp_mn_t(const float* x, const float* y, float* out) {
    float acc[32];
#pragma unroll
    for (int c = 0; c < 32; ++c) acc[c] = 0.f;
    gp_term<0>(x, y, acc);  gp_term<1>(x, y, acc);  gp_term<2>(x, y, acc);  gp_term<3>(x, y, acc);
    gp_term<4>(x, y, acc);  gp_term<5>(x, y, acc);  gp_term<6>(x, y, acc);  gp_term<7>(x, y, acc);
    gp_term<8>(x, y, acc);  gp_term<9>(x, y, acc);  gp_term<10>(x, y, acc); gp_term<11>(x, y, acc);
    gp_term<12>(x, y, acc); gp_term<13>(x, y, acc); gp_term<14>(x, y, acc); gp_term<15>(x, y, acc);
    gp_term<16>(x, y, acc); gp_term<17>(x, y, acc); gp_term<18>(x, y, acc); gp_term<19>(x, y, acc);
    gp_term<20>(x, y, acc); gp_term<21>(x, y, acc); gp_term<22>(x, y, acc); gp_term<23>(x, y, acc);
    gp_term<24>(x, y, acc); gp_term<25>(x, y, acc); gp_term<26>(x, y, acc); gp_term<27>(x, y, acc);
    gp_term<28>(x, y, acc); gp_term<29>(x, y, acc); gp_term<30>(x, y, acc); gp_term<31>(x, y, acc);
    float ss = 0.f;
#pragma unroll
    for (int c = 0; c < 32; ++c) ss = fmaf(acc[c], acc[c], ss);
    float r = 1.f / (sqrtf(ss) + 1e-6f);
#pragma unroll
    for (int c = 0; c < 32; ++c) out[c] = acc[c] * r;
}

__device__ __forceinline__ void leaf_load(const float* base, float* v) {
#pragma unroll
    for (int i = 0; i < 8; ++i) {
        const float4 f = *(const float4*)(base + i * 4);
        v[i * 4 + 0] = 0.5f * f.x; v[i * 4 + 1] = 0.5f * f.y;
        v[i * 4 + 2] = 0.5f * f.z; v[i * 4 + 3] = 0.5f * f.w;
    }
    v[0] += 1.f;
    float ss = 0.f;
#pragma unroll
    for (int c = 0; c < 32; ++c) ss = fmaf(v[c], v[c], ss);
    float r = 1.f / (sqrtf(ss) + 1e-6f);
#pragma unroll
    for (int c = 0; c < 32; ++c) v[c] *= r;
}

// ---------------- scan: wave per sequence, rotor per thread -----------------
__global__ __launch_bounds__(256) void scanreg_kernel(const float* __restrict__ DT,
                                                      float* __restrict__ pooled) {
    const int wave = threadIdx.x >> 6, lane = threadIdx.x & 63;
    const int seq = blockIdx.x * 4 + wave;               // b*64 + d
    const float* base = DT + ((size_t)seq * kS + lane * 4) * kG;

    float R[32], Y[32], P[32], Xa[32], Yb[32];

    leaf_load(base, R);
    for (int j = 1; j < 4; ++j) {
        leaf_load(base + j * kG, Y);
        gp_mn_t(Y, R, R);                                // later ∘ earlier
    }

    for (int step = 1; step < 64; step <<= 1) {
        const bool up = lane & step;
#pragma unroll
        for (int c = 0; c < 32; ++c) P[c] = __shfl_xor(R[c], step, 64);
#pragma unroll
        for (int c = 0; c < 32; ++c) {
            Xa[c] = up ? R[c] : P[c];
            Yb[c] = up ? P[c] : R[c];
        }
        gp_mn_t(Xa, Yb, R);
    }

    if (lane == 0) {
        float* op = pooled + (size_t)seq * kG;
#pragma unroll
        for (int i = 0; i < 8; ++i)
            *(float4*)(op + i * 4) = make_float4(R[i * 4], R[i * 4 + 1], R[i * 4 + 2], R[i * 4 + 3]);
    }
}

// ---------------- classifier: wave per class, pooled staged in LDS ----------
__global__ __launch_bounds__(256) void cls2_kernel(const float* __restrict__ P,
                                                   const float* __restrict__ Wc,
                                                   const float* __restrict__ bc,
                                                   float* __restrict__ out) {
    __shared__ float sp[kB * kDG];   // 64 KB
    const int tid = threadIdx.x, wave = tid >> 6, lane = tid & 63;
    for (int j = tid * 4; j < kB * kDG; j += 1024)
        *(float4*)&sp[j] = *(const float4*)(P + j);
    __syncthreads();

    const int c = blockIdx.x * 4 + wave;
    const float* w = Wc + (size_t)c * kDG;
    float acc[kB];
#pragma unroll
    for (int b = 0; b < kB; ++b) acc[b] = 0.f;
#pragma unroll
    for (int cc = 0; cc < 8; ++cc) {
        const float4 w4 = *(const float4*)(w + cc * 256 + lane * 4);
#pragma unroll
        for (int b = 0; b < kB; ++b) {
            const float4 p4 = *(const float4*)&sp[b * kDG + cc * 256 + lane * 4];
            acc[b] += w4.x * p4.x + w4.y * p4.y + w4.z * p4.z + w4.w * p4.w;
        }
    }
#pragma unroll
    for (int b = 0; b < kB; ++b)
#pragma unroll
        for (int off = 32; off > 0; off >>= 1) acc[b] += __shfl_xor(acc[b], off, 64);
    if (lane == 0) {
        float bias = bc[c];
#pragma unroll
        for (int b = 0; b < kB; ++b) out[b * kNC + c] = acc[b] + bias;
    }
}

extern "C" void kernel_launch(void* const* d_in, const int* in_sizes, int n_in,
                              void* d_out, int out_size, void* d_ws, size_t ws_size,
                              hipStream_t stream) {
    const float* x_in = (const float*)d_in[0];
    const float* Wq   = (const float*)d_in[1];
    const float* bq   = (const float*)d_in[2];
    const float* Wk   = (const float*)d_in[3];
    const float* bk   = (const float*)d_in[4];
    const float* Wv   = (const float*)d_in[5];
    const float* bv   = (const float*)d_in[6];
    const float* Wo   = (const float*)d_in[7];
    const float* bo   = (const float*)d_in[8];
    const float* ln1w = (const float*)d_in[9];
    const float* ln1b = (const float*)d_in[10];
    const float* ln2w = (const float*)d_in[11];
    const float* ln2b = (const float*)d_in[12];
    const float* gm1  = (const float*)d_in[13];
    const float* gm2  = (const float*)d_in[14];
    const float* W1   = (const float*)d_in[15];
    const float* b1   = (const float*)d_in[16];
    const float* W2   = (const float*)d_in[17];
    const float* b2   = (const float*)d_in[18];
    const float* Wr   = (const float*)d_in[19];
    const float* br   = (const float*)d_in[20];
    const float* Wc   = (const float*)d_in[21];
    const float* bc   = (const float*)d_in[22];

    const size_t NEL = (size_t)kT * kDG;
    float* F  = (float*)d_ws;
    float* X  = F;
    float* A  = F + NEL;
    float* Qb = F + 2 * NEL;
    float* Kb = F + 3 * NEL;
    float* Vb = F + 4 * NEL;
    unsigned short* Qh = (unsigned short*)Qb;   // bf16 Q/K/V (half the region)
    unsigned short* Kh = (unsigned short*)Kb;
    unsigned short* Vh = (unsigned short*)Vb;
    unsigned short* Mb = (unsigned short*)Kb;   // bf16 [t][32][256] = 32 MiB, spans Kb+Vb
    float* pooled = Qb;                         // 16K floats, Qb free at scan time

    ln_kernel<<<kT, 256, 0, stream>>>(x_in, ln1w, ln1b, A);

    for (int l = 0; l < 4; l++) {
        gemm_qkv_kernel<<<kT / 4, 256, 0, stream>>>(A,
            Wq + l * kD * kD, Wk + l * kD * kD, Wv + l * kD * kD,
            bq + l * kDG, bk + l * kDG, bv + l * kDG, Qh, Kh, Vh);
        attn_mfma_kernel<<<dim3(4, kNH, kB), 256, 0, stream>>>(Qh, Kh, Vh, A);
        gemmWo_fused_kernel<<<kT / 4, 256, 0, stream>>>(A, Wo + l * kD * kD, bo + l * kDG,
            l == 0 ? x_in : X, gm1 + l * kDG, ln2w + l * kDG, ln2b + l * kDG, X, A);
        mlp1_kernel<<<kT / 4, 256, 0, stream>>>(A, W1 + l * kE * kD, b1 + l * kE * kG, Mb);
        if (l < 3)
            mlp2_fused_kernel<true><<<kT / 4, 256, 0, stream>>>(Mb, W2 + l * kD * kE, b2 + l * kDG,
                X, gm2 + l * kDG, ln1w + (l + 1) * kDG, ln1b + (l + 1) * kDG, A);
        else
            mlp2_fused_kernel<false><<<kT / 4, 256, 0, stream>>>(Mb, W2 + l * kD * kE, b2 + l * kDG,
                X, gm2 + l * kDG, nullptr, nullptr, nullptr);
    }

    // delta (fp32, transposed layout) -> register-resident reduction -> classifier
    vlinT_kernel<<<kT, 256, 0, stream>>>(X, Wr, br, A);
    scanreg_kernel<<<kB * kD / 4, 256, 0, stream>>>(A, pooled);
    cls2_kernel<<<kNC / 4, 256, 0, stream>>>(pooled, Wc, bc, (float*)d_out);
}